// Round 12
// baseline (235.895 us; speedup 1.0000x reference)
//
#include <hip/hip_runtime.h>
#include <hip/hip_bf16.h>
#include <math.h>

#define BS 1024
#define D 128
#define NP 100000
#define PROWS 100096              // padded to multiple of 64 (96 zero rows)
#define NPG 1564                  // 64-proxy groups (= main grid)
#define NSLICE 16                 // rowsum slices (r11: 64 bought nothing)
#define LOG2E 1.44269504088896340736f

typedef float f32x4 __attribute__((ext_vector_type(4)));
typedef float f32x16 __attribute__((ext_vector_type(16)));
typedef __bf16 bf16x8 __attribute__((ext_vector_type(8)));
typedef unsigned short u16x8 __attribute__((ext_vector_type(8)));

#if defined(__has_builtin)
#if __has_builtin(__builtin_amdgcn_exp2f)
#define FAST_EXP2(x) __builtin_amdgcn_exp2f(x)
#endif
#endif
#ifndef FAST_EXP2
#define FAST_EXP2(x) exp2f(x)
#endif

static __device__ __forceinline__ unsigned short f2bf(float x) {
    unsigned int u = __float_as_uint(x);
    return (unsigned short)((u + 0x7fffu + ((u >> 16) & 1u)) >> 16);  // RNE
}

// ---------- kernel 1: batch -> bf16 Abat (FRAGMENT-READY), d_pos ----------
// Fragment-ready layout (validated rounds 3-11, absmax 0.0):
// element (row,k) at byte
//   ((row>>5)*8 + (k>>4))*1024 + ((k>>3)&1)*512 + (row&31)*16 + (k&7)*2
__global__ __launch_bounds__(256) void prep_kernel(
    const float* __restrict__ batch, const float* __restrict__ proxies,
    const int* __restrict__ labels, unsigned short* __restrict__ Abat,
    float* __restrict__ d_pos, float* __restrict__ rowsum,
    unsigned int* __restrict__ ctr, float* __restrict__ out)
{
    // zero the 16x1024 rowsum slices (128 blocks x 128 entries) + ctr + out
    if (threadIdx.x < 128) rowsum[blockIdx.x * 128 + threadIdx.x] = 0.f;
    if (blockIdx.x == 0 && threadIdx.x == 0) { out[0] = 0.f; ctr[0] = 0u; }

    int wave = threadIdx.x >> 6, lane = threadIdx.x & 63;
    int sub = lane >> 5, c = lane & 31;
    int row = blockIdx.x * 8 + wave * 2 + sub;   // 0..1023 (batch col)
    float4 v = *(const float4*)(batch + (size_t)row * D + c * 4);
    float ss = v.x*v.x + v.y*v.y + v.z*v.z + v.w*v.w;
    #pragma unroll
    for (int m = 1; m < 32; m <<= 1) ss += __shfl_xor(ss, m, 64);
    float sc = 3.0f / fmaxf(sqrtf(ss), 1e-12f);
    ushort4 pk;
    pk.x = f2bf(v.x*sc); pk.y = f2bf(v.y*sc);
    pk.z = f2bf(v.z*sc); pk.w = f2bf(v.w*sc);
    {
        int col_blk = row >> 5, lr = row & 31;
        int s = c >> 2, h2 = (c >> 1) & 1, j0 = (c & 1) * 4;
        size_t off = (((size_t)(col_blk * 8 + s) * 2 + h2) << 9) + lr * 16 + j0 * 2;
        *(ushort4*)((char*)Abat + off) = pk;
    }
    int lab = labels[row];
    float4 p4 = *(const float4*)(proxies + (size_t)lab * D + c * 4);
    float ps = p4.x*p4.x + p4.y*p4.y + p4.z*p4.z + p4.w*p4.w;
    #pragma unroll
    for (int m = 1; m < 32; m <<= 1) ps += __shfl_xor(ps, m, 64);
    float psc = 3.0f / fmaxf(sqrtf(ps), 1e-12f);
    float dt = (v.x*sc)*(p4.x*psc) + (v.y*sc)*(p4.y*psc)
             + (v.z*sc)*(p4.z*psc) + (v.w*sc)*(p4.w*psc);
    #pragma unroll
    for (int m = 1; m < 32; m <<= 1) dt += __shfl_xor(dt, m, 64);
    if (c == 0) d_pos[row] = 18.0f - 2.0f * dt;
}

// ---------- kernel 2: streaming GEMM + exp row-sums + FUSED FINAL ---------
// ROUND-10 BODY UNCHANGED (best total: 125.2us; r11 proved NSLICE and
// atomic contention are not the bottleneck). New: final_kernel is FOLDED
// in via the last-block-finishes pattern, deleting one kernel launch +
// inter-kernel graph gap (the total-minus-main ~70us slice is the target).
// Coherence audit (G16): rowsum is produced ONLY by device-scope atomicAdd
// and consumed via agent-scope atomic loads -> no cross-XCD stale-L2
// hazard. Release: per-thread __threadfence() before the ctr increment;
// acquire: __threadfence() after observing old==NPG-1. d_pos/Abat cross
// the prep kernel boundary (coherent).
// __launch_bounds__ law (rounds 1/2/4/5): arg=2 only. NEVER arg=4.
__global__ __launch_bounds__(256, 2) void main_kernel(
    const float* __restrict__ proxies,
    const unsigned short* __restrict__ Abat,   // batch, fragment-ready
    float* __restrict__ rowsum,                // [NSLICE][BS]
    const float* __restrict__ d_pos,
    unsigned int* __restrict__ ctr,
    float* __restrict__ out)
{
    __shared__ char Plds[64 * D * 2];          // 16 KB, fragment layout
    __shared__ float red[4];
    __shared__ unsigned int isLast;
    const int tid = threadIdx.x;
    const int lane = tid & 63;
    const int wave = tid >> 6;                 // 0..3 = batch quarter
    const int l31 = lane & 31, hi = lane >> 5;
    const int pg = blockIdx.x;                 // 64-proxy group

    // ---- staging: p = tid>>2 (0..63), q = tid&3 (32 floats each) ---------
    {
        int p = tid >> 2, q = tid & 3;
        int pidx = pg * 64 + p;
        const float* src = proxies + (size_t)pidx * D + q * 32;
        float ss = 0.f;
        if (pidx < NP) {
            #pragma unroll
            for (int j = 0; j < 8; ++j) {
                float4 v = *(const float4*)(src + j * 4);
                ss += v.x*v.x + v.y*v.y + v.z*v.z + v.w*v.w;
            }
        }
        ss += __shfl_xor(ss, 1, 64);             // combine 4 quarters
        ss += __shfl_xor(ss, 2, 64);
        float sc = 3.0f / fmaxf(sqrtf(ss), 1e-12f);
        #pragma unroll
        for (int i2 = 0; i2 < 4; ++i2) {
            u16x8 w = (u16x8){0,0,0,0,0,0,0,0};
            if (pidx < NP) {
                float4 a = *(const float4*)(src + i2 * 8);      // L1 hit
                float4 b = *(const float4*)(src + i2 * 8 + 4);
                w[0] = f2bf(a.x*sc); w[1] = f2bf(a.y*sc);
                w[2] = f2bf(a.z*sc); w[3] = f2bf(a.w*sc);
                w[4] = f2bf(b.x*sc); w[5] = f2bf(b.y*sc);
                w[6] = f2bf(b.z*sc); w[7] = f2bf(b.w*sc);
            }
            int cl = q * 4 + i2;                 // 16B k-chunk index
            size_t off = ((size_t)((p >> 5) * 8 + (cl >> 1)) << 10)
                       + ((size_t)(cl & 1) << 9) + (p & 31) * 16;
            *(u16x8*)(Plds + off) = w;
        }
    }
    __syncthreads();

    // ---- Af cache: 64 proxies x K=128, 16 ds_read_b128, AGPR-resident ----
    bf16x8 Af[2][8];
    #pragma unroll
    for (int t = 0; t < 2; ++t) {
        #pragma unroll
        for (int s = 0; s < 8; ++s)
            Af[t][s] = *(const bf16x8*)(Plds + (((t << 3) | s) << 10) + lane * 16);
    }

    const float c1 = 2.0f * LOG2E, c0 = -18.0f * LOG2E;
    float* rs_base = rowsum + (size_t)(pg & (NSLICE - 1)) * BS;

    auto loadB = [&](bf16x8 (&Bf)[8], int cb) {
        const char* bp = (const char*)Abat + ((size_t)cb << 13) + lane * 16;
        #pragma unroll
        for (int s = 0; s < 8; ++s)
            Bf[s] = *(const bf16x8*)(bp + ((size_t)s << 10));
    };
    auto do_cb = [&](const bf16x8 (&Bf)[8], int cb) {
        f32x16 a0 = {0.f,0.f,0.f,0.f,0.f,0.f,0.f,0.f,
                     0.f,0.f,0.f,0.f,0.f,0.f,0.f,0.f};
        f32x16 a1 = a0;
        #pragma unroll
        for (int s = 0; s < 8; ++s) {
            a0 = __builtin_amdgcn_mfma_f32_32x32x16_bf16(Af[0][s], Bf[s], a0, 0, 0, 0);
            a1 = __builtin_amdgcn_mfma_f32_32x32x16_bf16(Af[1][s], Bf[s], a1, 0, 0, 0);
        }
        float e0 = 0.f, e1 = 0.f, e2 = 0.f, e3 = 0.f;
        #pragma unroll
        for (int r = 0; r < 4; ++r) {
            e0 += FAST_EXP2(fmaf(a0[4*r+0], c1, c0));
            e1 += FAST_EXP2(fmaf(a0[4*r+1], c1, c0));
            e2 += FAST_EXP2(fmaf(a0[4*r+2], c1, c0));
            e3 += FAST_EXP2(fmaf(a0[4*r+3], c1, c0));
            e0 += FAST_EXP2(fmaf(a1[4*r+0], c1, c0));
            e1 += FAST_EXP2(fmaf(a1[4*r+1], c1, c0));
            e2 += FAST_EXP2(fmaf(a1[4*r+2], c1, c0));
            e3 += FAST_EXP2(fmaf(a1[4*r+3], c1, c0));
        }
        float rs = (e0 + e1) + (e2 + e3);
        rs += __shfl_xor(rs, 32, 64);            // combine the two row-halves
        if (hi == 0)
            atomicAdd(rs_base + cb * 32 + l31, rs);
    };

    // ---- 8 col-blocks (this wave's 256 batch cols), Bf double-buffered ---
    bf16x8 Bf0[8], Bf1[8];
    const int cb0 = wave * 8;
    loadB(Bf0, cb0);
    #pragma unroll 1
    for (int j = 0; j < 4; ++j) {
        loadB(Bf1, cb0 + 2 * j + 1);     // prefetch flies under do_cb's MFMAs
        do_cb(Bf0, cb0 + 2 * j);
        if (j < 3) loadB(Bf0, cb0 + 2 * j + 2);
        do_cb(Bf1, cb0 + 2 * j + 1);
    }

    // ---- fused final: last block to arrive does the LSE+mean reduction ---
    __threadfence();                         // release this block's atomics
    __syncthreads();                         // all threads past their fence
    if (tid == 0) {
        unsigned int old = atomicAdd(ctr, 1u);
        isLast = (old == (unsigned int)(NPG - 1)) ? 1u : 0u;
    }
    __syncthreads();
    if (isLast) {
        __threadfence();                     // acquire: all blocks' atomics
        float acc = 0.f;
        #pragma unroll
        for (int rr = 0; rr < 4; ++rr) {
            int row = tid + rr * 256;
            float tot = 0.f;
            #pragma unroll
            for (int s = 0; s < NSLICE; ++s)
                tot += __hip_atomic_load(&rowsum[(size_t)s * BS + row],
                                         __ATOMIC_RELAXED, __HIP_MEMORY_SCOPE_AGENT);
            float dp = d_pos[row];
            const float PADC = 96.0f * exp2f(-18.0f * LOG2E);  // zero-pad rows
            float neg = tot - expf(-dp) - PADC;                // drop own col
            acc += dp + logf(fmaxf(neg, 1e-37f));
        }
        #pragma unroll
        for (int m = 1; m < 64; m <<= 1) acc += __shfl_xor(acc, m, 64);
        if (lane == 0) red[wave] = acc;
        __syncthreads();
        if (tid == 0)
            out[0] = ((red[0] + red[1]) + (red[2] + red[3])) * (1.0f / 1024.0f);
    }
}

extern "C" void kernel_launch(void* const* d_in, const int* in_sizes, int n_in,
                              void* d_out, int out_size, void* d_ws, size_t ws_size,
                              hipStream_t stream) {
    const float* batch   = (const float*)d_in[0];
    const float* proxies = (const float*)d_in[1];
    const int*   labels  = (const int*)d_in[2];
    float* out = (float*)d_out;

    char* ws = (char*)d_ws;
    unsigned short* A  = (unsigned short*)ws;                    //   262,144 B
    float* d_pos       = (float*)(ws + 262144);                  //     4,096 B
    float* rowsum      = (float*)(ws + 266240);                  //    65,536 B
    unsigned int* ctr  = (unsigned int*)(ws + 331776);           //         4 B

    prep_kernel<<<128, 256, 0, stream>>>(batch, proxies, labels, A, d_pos, rowsum, ctr, out);
    main_kernel<<<NPG, 256, 0, stream>>>(proxies, A, rowsum, d_pos, ctr, out);
}

// Round 13
// 136.178 us; speedup vs baseline: 1.7322x; 1.7322x over previous
//
#include <hip/hip_runtime.h>
#include <hip/hip_bf16.h>
#include <math.h>

#define BS 1024
#define D 128
#define NP 100000
#define PROWS 100096              // padded to multiple of 64 (96 zero rows)
#define NPG 1564                  // 64-proxy groups (= main grid)
#define NSLICE 16                 // rowsum slices
#define LOG2E 1.44269504088896340736f

typedef float f32x4 __attribute__((ext_vector_type(4)));
typedef float f32x16 __attribute__((ext_vector_type(16)));
typedef __bf16 bf16x8 __attribute__((ext_vector_type(8)));
typedef unsigned short u16x8 __attribute__((ext_vector_type(8)));

#if defined(__has_builtin)
#if __has_builtin(__builtin_amdgcn_exp2f)
#define FAST_EXP2(x) __builtin_amdgcn_exp2f(x)
#endif
#endif
#ifndef FAST_EXP2
#define FAST_EXP2(x) exp2f(x)
#endif

static __device__ __forceinline__ unsigned short f2bf(float x) {
    unsigned int u = __float_as_uint(x);
    return (unsigned short)((u + 0x7fffu + ((u >> 16) & 1u)) >> 16);  // RNE
}

// ---------- kernel 1: batch -> bf16 Abat (FRAGMENT-READY), d_pos ----------
// Fragment-ready layout (validated rounds 3-12, absmax 0.0):
// element (row,k) at byte
//   ((row>>5)*8 + (k>>4))*1024 + ((k>>3)&1)*512 + (row&31)*16 + (k&7)*2
__global__ __launch_bounds__(256) void prep_kernel(
    const float* __restrict__ batch, const float* __restrict__ proxies,
    const int* __restrict__ labels, unsigned short* __restrict__ Abat,
    float* __restrict__ d_pos, float* __restrict__ rowsum,
    float* __restrict__ out)
{
    // zero the 16x1024 rowsum slices (128 blocks x 128 entries)
    if (threadIdx.x < 128) rowsum[blockIdx.x * 128 + threadIdx.x] = 0.f;
    if (blockIdx.x == 0 && threadIdx.x == 0) out[0] = 0.f;

    int wave = threadIdx.x >> 6, lane = threadIdx.x & 63;
    int sub = lane >> 5, c = lane & 31;
    int row = blockIdx.x * 8 + wave * 2 + sub;   // 0..1023 (batch col)
    float4 v = *(const float4*)(batch + (size_t)row * D + c * 4);
    float ss = v.x*v.x + v.y*v.y + v.z*v.z + v.w*v.w;
    #pragma unroll
    for (int m = 1; m < 32; m <<= 1) ss += __shfl_xor(ss, m, 64);
    float sc = 3.0f / fmaxf(sqrtf(ss), 1e-12f);
    ushort4 pk;
    pk.x = f2bf(v.x*sc); pk.y = f2bf(v.y*sc);
    pk.z = f2bf(v.z*sc); pk.w = f2bf(v.w*sc);
    {
        int col_blk = row >> 5, lr = row & 31;
        int s = c >> 2, h2 = (c >> 1) & 1, j0 = (c & 1) * 4;
        size_t off = (((size_t)(col_blk * 8 + s) * 2 + h2) << 9) + lr * 16 + j0 * 2;
        *(ushort4*)((char*)Abat + off) = pk;
    }
    int lab = labels[row];
    float4 p4 = *(const float4*)(proxies + (size_t)lab * D + c * 4);
    float ps = p4.x*p4.x + p4.y*p4.y + p4.z*p4.z + p4.w*p4.w;
    #pragma unroll
    for (int m = 1; m < 32; m <<= 1) ps += __shfl_xor(ps, m, 64);
    float psc = 3.0f / fmaxf(sqrtf(ps), 1e-12f);
    float dt = (v.x*sc)*(p4.x*psc) + (v.y*sc)*(p4.y*psc)
             + (v.z*sc)*(p4.z*psc) + (v.w*sc)*(p4.w*psc);
    #pragma unroll
    for (int m = 1; m < 32; m <<= 1) dt += __shfl_xor(dt, m, 64);
    if (c == 0) d_pos[row] = 18.0f - 2.0f * dt;
}

// ---------- kernel 2: streaming GEMM + exp row-sums -----------------------
// ROUND-12 FUSION REVERTED (per-block device __threadfence forces an L2
// writeback on multi-XCD gfx950: 1564 drains = 3.5x slowdown. Never fuse
// via per-block device fences on this arch.)
// NEW: true 4-blocks/CU residency. Measured occupancy has been ~23% = 2
// blocks/CU in ALL (x,2) rounds -- __launch_bounds__ arg2 caps BOTH regs
// (256/arg2) and residency (arg2 blocks of 256). This round slims the
// working set to genuinely fit arg2=4's 64-VGPR/64-AGPR budget:
//   wave = (proxy-half ph, col-half ch): 32 proxies x 512 cols (16 cbs).
//   Af[8] = 32 AGPR, acc = 16 AGPR, single Bf[8] = 32 VGPR (no dbuf).
// (r9 precedent: this streaming style compiled to 56 VGPR.) 16 waves/CU
// doubles latency-hiding TLP; grid 1564x4 = 6256 waves = 24.4/CU supply.
__global__ __launch_bounds__(256, 4) void main_kernel(
    const float* __restrict__ proxies,
    const unsigned short* __restrict__ Abat,   // batch, fragment-ready
    float* __restrict__ rowsum)                // [NSLICE][BS]
{
    __shared__ char Plds[64 * D * 2];          // 16 KB, fragment layout
    const int tid = threadIdx.x;
    const int lane = tid & 63;
    const int wave = tid >> 6;                 // 0..3
    const int l31 = lane & 31, hi = lane >> 5;
    const int pg = blockIdx.x;                 // 64-proxy group

    // ---- staging: p = tid>>2 (0..63), q = tid&3 (32 floats each) ---------
    {
        int p = tid >> 2, q = tid & 3;
        int pidx = pg * 64 + p;
        const float* src = proxies + (size_t)pidx * D + q * 32;
        float ss = 0.f;
        if (pidx < NP) {
            #pragma unroll
            for (int j = 0; j < 8; ++j) {
                float4 v = *(const float4*)(src + j * 4);
                ss += v.x*v.x + v.y*v.y + v.z*v.z + v.w*v.w;
            }
        }
        ss += __shfl_xor(ss, 1, 64);             // combine 4 quarters
        ss += __shfl_xor(ss, 2, 64);
        float sc = 3.0f / fmaxf(sqrtf(ss), 1e-12f);
        #pragma unroll
        for (int i2 = 0; i2 < 4; ++i2) {
            u16x8 w = (u16x8){0,0,0,0,0,0,0,0};
            if (pidx < NP) {
                float4 a = *(const float4*)(src + i2 * 8);      // L1 hit
                float4 b = *(const float4*)(src + i2 * 8 + 4);
                w[0] = f2bf(a.x*sc); w[1] = f2bf(a.y*sc);
                w[2] = f2bf(a.z*sc); w[3] = f2bf(a.w*sc);
                w[4] = f2bf(b.x*sc); w[5] = f2bf(b.y*sc);
                w[6] = f2bf(b.z*sc); w[7] = f2bf(b.w*sc);
            }
            int cl = q * 4 + i2;                 // 16B k-chunk index
            size_t off = ((size_t)((p >> 5) * 8 + (cl >> 1)) << 10)
                       + ((size_t)(cl & 1) << 9) + (p & 31) * 16;
            *(u16x8*)(Plds + off) = w;
        }
    }
    __syncthreads();

    const int ph = wave >> 1;                  // proxy half (32 proxies)
    const int ch = wave & 1;                   // col half (512 cols, 16 cbs)

    // ---- Af cache: 32 proxies x K=128 = 32 AGPR, read LDS once -----------
    bf16x8 Af[8];
    #pragma unroll
    for (int s = 0; s < 8; ++s)
        Af[s] = *(const bf16x8*)(Plds + (((ph << 3) | s) << 10) + lane * 16);

    const float c1 = 2.0f * LOG2E, c0 = -18.0f * LOG2E;
    float* rs_base = rowsum + (size_t)(((pg << 1) | ph) & (NSLICE - 1)) * BS;

    #pragma unroll 1
    for (int cb = ch * 16; cb < ch * 16 + 16; ++cb) {
        // Bf: 32 cols x K=128, 8 coalesced 1KB loads from L2-resident Abat
        const char* bp = (const char*)Abat + ((size_t)cb << 13) + lane * 16;
        bf16x8 Bf[8];
        #pragma unroll
        for (int s = 0; s < 8; ++s)
            Bf[s] = *(const bf16x8*)(bp + ((size_t)s << 10));

        f32x16 a = {0.f,0.f,0.f,0.f,0.f,0.f,0.f,0.f,
                    0.f,0.f,0.f,0.f,0.f,0.f,0.f,0.f};
        #pragma unroll
        for (int s = 0; s < 8; ++s)
            a = __builtin_amdgcn_mfma_f32_32x32x16_bf16(Af[s], Bf[s], a, 0, 0, 0);

        // epilogue: lane's batch col = cb*32 + l31; 16 of this wave's 32
        // proxy rows per lane (other 16 in the hi^1 half-wave).
        float e0 = 0.f, e1 = 0.f, e2 = 0.f, e3 = 0.f;
        #pragma unroll
        for (int r = 0; r < 4; ++r) {
            e0 += FAST_EXP2(fmaf(a[4*r+0], c1, c0));
            e1 += FAST_EXP2(fmaf(a[4*r+1], c1, c0));
            e2 += FAST_EXP2(fmaf(a[4*r+2], c1, c0));
            e3 += FAST_EXP2(fmaf(a[4*r+3], c1, c0));
        }
        float rs = (e0 + e1) + (e2 + e3);
        rs += __shfl_xor(rs, 32, 64);            // combine the two row-halves
        if (hi == 0)
            atomicAdd(rs_base + cb * 32 + l31, rs);
    }
}

// ---------- kernel 3: final lse + mean (4 blocks, atomicAdd out) ----------
__global__ __launch_bounds__(256) void final_kernel(
    const float* __restrict__ rowsum, const float* __restrict__ d_pos,
    float* __restrict__ out)
{
    int row = blockIdx.x * 256 + threadIdx.x;
    float tot = 0.f;
    #pragma unroll
    for (int s = 0; s < NSLICE; ++s)
        tot += rowsum[(size_t)s * BS + row];
    float dp = d_pos[row];
    const float PADC = 96.0f * exp2f(-18.0f * LOG2E);  // zero-pad rows
    float neg = tot - expf(-dp) - PADC;                // drop own column
    float val = dp + logf(fmaxf(neg, 1e-37f));
    #pragma unroll
    for (int m = 1; m < 64; m <<= 1) val += __shfl_xor(val, m, 64);
    __shared__ float red[4];
    if ((threadIdx.x & 63) == 0) red[threadIdx.x >> 6] = val;
    __syncthreads();
    if (threadIdx.x == 0) {
        float v = (red[0] + red[1]) + (red[2] + red[3]);
        atomicAdd(out, v * (1.0f / 1024.0f));
    }
}

extern "C" void kernel_launch(void* const* d_in, const int* in_sizes, int n_in,
                              void* d_out, int out_size, void* d_ws, size_t ws_size,
                              hipStream_t stream) {
    const float* batch   = (const float*)d_in[0];
    const float* proxies = (const float*)d_in[1];
    const int*   labels  = (const int*)d_in[2];
    float* out = (float*)d_out;

    char* ws = (char*)d_ws;
    unsigned short* A  = (unsigned short*)ws;                    //   262,144 B
    float* d_pos       = (float*)(ws + 262144);                  //     4,096 B
    float* rowsum      = (float*)(ws + 266240);                  //    65,536 B

    prep_kernel<<<128, 256, 0, stream>>>(batch, proxies, labels, A, d_pos, rowsum, out);
    main_kernel<<<NPG, 256, 0, stream>>>(proxies, A, rowsum);
    final_kernel<<<4, 256, 0, stream>>>(rowsum, d_pos, out);
}

// Round 14
// 121.853 us; speedup vs baseline: 1.9359x; 1.1176x over previous
//
#include <hip/hip_runtime.h>
#include <hip/hip_bf16.h>
#include <math.h>

#define BS 1024
#define D 128
#define NP 100000
#define PROWS 100096              // padded to multiple of 64 (96 zero rows)
#define NPG 1564                  // 64-proxy groups (= main grid)
#define NSLICE 16                 // rowsum slices
#define LOG2E 1.44269504088896340736f

typedef float f32x4 __attribute__((ext_vector_type(4)));
typedef float f32x16 __attribute__((ext_vector_type(16)));
typedef __bf16 bf16x8 __attribute__((ext_vector_type(8)));
typedef unsigned short u16x8 __attribute__((ext_vector_type(8)));

#if defined(__has_builtin)
#if __has_builtin(__builtin_amdgcn_exp2f)
#define FAST_EXP2(x) __builtin_amdgcn_exp2f(x)
#endif
#endif
#ifndef FAST_EXP2
#define FAST_EXP2(x) exp2f(x)
#endif

static __device__ __forceinline__ unsigned short f2bf(float x) {
    unsigned int u = __float_as_uint(x);
    return (unsigned short)((u + 0x7fffu + ((u >> 16) & 1u)) >> 16);  // RNE
}

// ---------- kernel 1: batch -> bf16 Abat (FRAGMENT-READY), d_pos ----------
// Fragment-ready layout (validated rounds 3-13, absmax 0.0):
// element (row,k) at byte
//   ((row>>5)*8 + (k>>4))*1024 + ((k>>3)&1)*512 + (row&31)*16 + (k&7)*2
__global__ __launch_bounds__(256) void prep_kernel(
    const float* __restrict__ batch, const float* __restrict__ proxies,
    const int* __restrict__ labels, unsigned short* __restrict__ Abat,
    float* __restrict__ d_pos, float* __restrict__ rowsum,
    float* __restrict__ out)
{
    // zero the 16x1024 rowsum slices (128 blocks x 128 entries)
    if (threadIdx.x < 128) rowsum[blockIdx.x * 128 + threadIdx.x] = 0.f;
    if (blockIdx.x == 0 && threadIdx.x == 0) out[0] = 0.f;

    int wave = threadIdx.x >> 6, lane = threadIdx.x & 63;
    int sub = lane >> 5, c = lane & 31;
    int row = blockIdx.x * 8 + wave * 2 + sub;   // 0..1023 (batch col)
    float4 v = *(const float4*)(batch + (size_t)row * D + c * 4);
    float ss = v.x*v.x + v.y*v.y + v.z*v.z + v.w*v.w;
    #pragma unroll
    for (int m = 1; m < 32; m <<= 1) ss += __shfl_xor(ss, m, 64);
    float sc = 3.0f / fmaxf(sqrtf(ss), 1e-12f);
    ushort4 pk;
    pk.x = f2bf(v.x*sc); pk.y = f2bf(v.y*sc);
    pk.z = f2bf(v.z*sc); pk.w = f2bf(v.w*sc);
    {
        int col_blk = row >> 5, lr = row & 31;
        int s = c >> 2, h2 = (c >> 1) & 1, j0 = (c & 1) * 4;
        size_t off = (((size_t)(col_blk * 8 + s) * 2 + h2) << 9) + lr * 16 + j0 * 2;
        *(ushort4*)((char*)Abat + off) = pk;
    }
    int lab = labels[row];
    float4 p4 = *(const float4*)(proxies + (size_t)lab * D + c * 4);
    float ps = p4.x*p4.x + p4.y*p4.y + p4.z*p4.z + p4.w*p4.w;
    #pragma unroll
    for (int m = 1; m < 32; m <<= 1) ps += __shfl_xor(ps, m, 64);
    float psc = 3.0f / fmaxf(sqrtf(ps), 1e-12f);
    float dt = (v.x*sc)*(p4.x*psc) + (v.y*sc)*(p4.y*psc)
             + (v.z*sc)*(p4.z*psc) + (v.w*sc)*(p4.w*psc);
    #pragma unroll
    for (int m = 1; m < 32; m <<= 1) dt += __shfl_xor(dt, m, 64);
    if (c == 0) d_pos[row] = 18.0f - 2.0f * dt;
}

// ---------- kernel 2: streaming GEMM + exp row-sums -----------------------
// ROUND-10 BASE (best total 125.2us) + 2-DEEP CB SOFTWARE PIPELINE:
// program order now issues chain(cb+1)'s MFMAs BEFORE epilogue(cb)'s
// VALU, so the MFMA pipe grinds cb+1 while VALU crunches cb's exp/atomic
// (separate pipes, m114). Previously the ~400cy epilogue sat serially
// between chains. Statically-named acc pairs A0/A1/B0/B1 (runtime-indexed
// acc arrays would spill to scratch). Register budget: Af 64 + acc 64 =
// 128 AGPR; Bf0/Bf1 64 + misc ~30 VGPR <= 128. (256,2) as always.
// r13 lesson: occupancy x2 = neutral (latency not TLP-absorbable) and
// halving per-wave Bf reuse costs ~+10us of TCP line traffic. Keep 64
// proxies/wave.
__global__ __launch_bounds__(256, 2) void main_kernel(
    const float* __restrict__ proxies,
    const unsigned short* __restrict__ Abat,   // batch, fragment-ready
    float* __restrict__ rowsum)                // [NSLICE][BS]
{
    __shared__ char Plds[64 * D * 2];          // 16 KB, fragment layout
    const int tid = threadIdx.x;
    const int lane = tid & 63;
    const int wave = tid >> 6;                 // 0..3 = batch quarter
    const int l31 = lane & 31, hi = lane >> 5;
    const int pg = blockIdx.x;                 // 64-proxy group

    // ---- staging: p = tid>>2 (0..63), q = tid&3 (32 floats each) ---------
    {
        int p = tid >> 2, q = tid & 3;
        int pidx = pg * 64 + p;
        const float* src = proxies + (size_t)pidx * D + q * 32;
        float ss = 0.f;
        if (pidx < NP) {
            #pragma unroll
            for (int j = 0; j < 8; ++j) {
                float4 v = *(const float4*)(src + j * 4);
                ss += v.x*v.x + v.y*v.y + v.z*v.z + v.w*v.w;
            }
        }
        ss += __shfl_xor(ss, 1, 64);             // combine 4 quarters
        ss += __shfl_xor(ss, 2, 64);
        float sc = 3.0f / fmaxf(sqrtf(ss), 1e-12f);
        #pragma unroll
        for (int i2 = 0; i2 < 4; ++i2) {
            u16x8 w = (u16x8){0,0,0,0,0,0,0,0};
            if (pidx < NP) {
                float4 a = *(const float4*)(src + i2 * 8);      // L1 hit
                float4 b = *(const float4*)(src + i2 * 8 + 4);
                w[0] = f2bf(a.x*sc); w[1] = f2bf(a.y*sc);
                w[2] = f2bf(a.z*sc); w[3] = f2bf(a.w*sc);
                w[4] = f2bf(b.x*sc); w[5] = f2bf(b.y*sc);
                w[6] = f2bf(b.z*sc); w[7] = f2bf(b.w*sc);
            }
            int cl = q * 4 + i2;                 // 16B k-chunk index
            size_t off = ((size_t)((p >> 5) * 8 + (cl >> 1)) << 10)
                       + ((size_t)(cl & 1) << 9) + (p & 31) * 16;
            *(u16x8*)(Plds + off) = w;
        }
    }
    __syncthreads();

    // ---- Af cache: 64 proxies x K=128, 16 ds_read_b128, AGPR-resident ----
    bf16x8 Af[2][8];
    #pragma unroll
    for (int t = 0; t < 2; ++t) {
        #pragma unroll
        for (int s = 0; s < 8; ++s)
            Af[t][s] = *(const bf16x8*)(Plds + (((t << 3) | s) << 10) + lane * 16);
    }

    const float c1 = 2.0f * LOG2E, c0 = -18.0f * LOG2E;
    float* rs_base = rowsum + (size_t)(pg & (NSLICE - 1)) * BS;

    auto loadB = [&](bf16x8 (&Bf)[8], int cb) {
        const char* bp = (const char*)Abat + ((size_t)cb << 13) + lane * 16;
        #pragma unroll
        for (int s = 0; s < 8; ++s)
            Bf[s] = *(const bf16x8*)(bp + ((size_t)s << 10));
    };
    auto chain = [&](const bf16x8 (&Bf)[8], f32x16 &x0, f32x16 &x1) {
        x0 = (f32x16){0.f,0.f,0.f,0.f,0.f,0.f,0.f,0.f,
                      0.f,0.f,0.f,0.f,0.f,0.f,0.f,0.f};
        x1 = x0;
        #pragma unroll
        for (int s = 0; s < 8; ++s) {
            x0 = __builtin_amdgcn_mfma_f32_32x32x16_bf16(Af[0][s], Bf[s], x0, 0, 0, 0);
            x1 = __builtin_amdgcn_mfma_f32_32x32x16_bf16(Af[1][s], Bf[s], x1, 0, 0, 0);
        }
    };
    auto epi = [&](const f32x16 &x0, const f32x16 &x1, int cb) {
        float e0 = 0.f, e1 = 0.f, e2 = 0.f, e3 = 0.f;
        #pragma unroll
        for (int r = 0; r < 4; ++r) {
            e0 += FAST_EXP2(fmaf(x0[4*r+0], c1, c0));
            e1 += FAST_EXP2(fmaf(x0[4*r+1], c1, c0));
            e2 += FAST_EXP2(fmaf(x0[4*r+2], c1, c0));
            e3 += FAST_EXP2(fmaf(x0[4*r+3], c1, c0));
            e0 += FAST_EXP2(fmaf(x1[4*r+0], c1, c0));
            e1 += FAST_EXP2(fmaf(x1[4*r+1], c1, c0));
            e2 += FAST_EXP2(fmaf(x1[4*r+2], c1, c0));
            e3 += FAST_EXP2(fmaf(x1[4*r+3], c1, c0));
        }
        float rs = (e0 + e1) + (e2 + e3);
        rs += __shfl_xor(rs, 32, 64);            // combine the two row-halves
        if (hi == 0)
            atomicAdd(rs_base + cb * 32 + l31, rs);
    };

    // ---- 8 col-blocks, 2-deep pipeline: chain(k+1) issued before epi(k) --
    bf16x8 Bf0[8], Bf1[8];
    f32x16 A0, A1, B0, B1;                      // statically-named acc pairs
    const int cb0 = wave * 8;
    loadB(Bf0, cb0);
    loadB(Bf1, cb0 + 1);
    chain(Bf0, A0, A1);                          // cb0
    #pragma unroll 1
    for (int j = 0; j < 3; ++j) {
        chain(Bf1, B0, B1);                      // cb0+2j+1 (MFMA pipe)
        loadB(Bf0, cb0 + 2 * j + 2);             // prefetch
        epi(A0, A1, cb0 + 2 * j);                // VALU overlaps chain above
        chain(Bf0, A0, A1);                      // cb0+2j+2
        loadB(Bf1, cb0 + 2 * j + 3);
        epi(B0, B1, cb0 + 2 * j + 1);
    }
    chain(Bf1, B0, B1);                          // cb0+7
    epi(A0, A1, cb0 + 6);
    epi(B0, B1, cb0 + 7);
}

// ---------- kernel 3: final lse + mean (4 blocks, atomicAdd out) ----------
__global__ __launch_bounds__(256) void final_kernel(
    const float* __restrict__ rowsum, const float* __restrict__ d_pos,
    float* __restrict__ out)
{
    int row = blockIdx.x * 256 + threadIdx.x;
    float tot = 0.f;
    #pragma unroll
    for (int s = 0; s < NSLICE; ++s)
        tot += rowsum[(size_t)s * BS + row];
    float dp = d_pos[row];
    const float PADC = 96.0f * exp2f(-18.0f * LOG2E);  // zero-pad rows
    float neg = tot - expf(-dp) - PADC;                // drop own column
    float val = dp + logf(fmaxf(neg, 1e-37f));
    #pragma unroll
    for (int m = 1; m < 64; m <<= 1) val += __shfl_xor(val, m, 64);
    __shared__ float red[4];
    if ((threadIdx.x & 63) == 0) red[threadIdx.x >> 6] = val;
    __syncthreads();
    if (threadIdx.x == 0) {
        float v = (red[0] + red[1]) + (red[2] + red[3]);
        atomicAdd(out, v * (1.0f / 1024.0f));
    }
}

extern "C" void kernel_launch(void* const* d_in, const int* in_sizes, int n_in,
                              void* d_out, int out_size, void* d_ws, size_t ws_size,
                              hipStream_t stream) {
    const float* batch   = (const float*)d_in[0];
    const float* proxies = (const float*)d_in[1];
    const int*   labels  = (const int*)d_in[2];
    float* out = (float*)d_out;

    char* ws = (char*)d_ws;
    unsigned short* A  = (unsigned short*)ws;                    //   262,144 B
    float* d_pos       = (float*)(ws + 262144);                  //     4,096 B
    float* rowsum      = (float*)(ws + 266240);                  //    65,536 B

    prep_kernel<<<128, 256, 0, stream>>>(batch, proxies, labels, A, d_pos, rowsum, out);
    main_kernel<<<NPG, 256, 0, stream>>>(proxies, A, rowsum);
    final_kernel<<<4, 256, 0, stream>>>(rowsum, d_pos, out);
}